// Round 1
// baseline (12519.389 us; speedup 1.0000x reference)
//
#include <hip/hip_runtime.h>

// CAGenerator: 64-step neural cellular automaton.
// State layout: S[c][n], n = b*1024 + y*32 + x  (C x 8192).
// Per step: premask -> im2col -> GEMM(512,720) -> GEMM(512,512,relu) ->
//           GEMM(80,512,+state) -> mask/update.
// mask = uniform()<1.0 in the reference is ALWAYS true -> no RNG needed.
// ws usage: ~48.3 MB (see layout in kernel_launch).

#define NPIX 8192          // 8 * 32 * 32
#define T_ALIVE 0.01f

// ---------------------------------------------------------------------------
// Generic fp32 GEMM: C[M][NPIX] = A^T * B (+bias) (opt relu) (opt +addsrc)
//   A: K x M (pre-transposed weights), B: K x NPIX.
// Tiles: 64x64 block, BK=16, 4x4 per thread, 256 threads.
// ---------------------------------------------------------------------------
__global__ __launch_bounds__(256) void gemm64(
    const float* __restrict__ A,
    const float* __restrict__ B,
    const float* __restrict__ bias,
    const float* __restrict__ addsrc,   // M x NPIX or nullptr
    float* __restrict__ C,
    int M, int K, int relu)
{
    __shared__ float As[16][64];
    __shared__ float Bs[16][64];
    const int tid = threadIdx.x;
    const int tx = tid & 15, ty = tid >> 4;
    const int m0 = blockIdx.y * 64;
    const int n0 = blockIdx.x * 64;

    float acc[4][4];
#pragma unroll
    for (int i = 0; i < 4; ++i)
#pragma unroll
        for (int j = 0; j < 4; ++j) acc[i][j] = 0.f;

    const int la  = tid * 4;       // 1024 elems / 256 threads = 4 each
    const int lak = la >> 6;       // k row within tile
    const int lam = la & 63;       // col within tile

    for (int k0 = 0; k0 < K; k0 += 16) {
        // ---- stage A tile (guard only needed for the M=80 edge block) ----
        {
            const float* src = A + (size_t)(k0 + lak) * M + m0 + lam;
            float4 v;
            if (m0 + 64 <= M) {
                v = *(const float4*)src;
            } else {
                v.x = (m0 + lam + 0 < M) ? src[0] : 0.f;
                v.y = (m0 + lam + 1 < M) ? src[1] : 0.f;
                v.z = (m0 + lam + 2 < M) ? src[2] : 0.f;
                v.w = (m0 + lam + 3 < M) ? src[3] : 0.f;
            }
            *(float4*)&As[lak][lam] = v;
        }
        // ---- stage B tile (always in-bounds) ----
        {
            const float* src = B + (size_t)(k0 + lak) * NPIX + n0 + lam;
            *(float4*)&Bs[lak][lam] = *(const float4*)src;
        }
        __syncthreads();
#pragma unroll
        for (int kk = 0; kk < 16; ++kk) {
            float4 a4 = *(const float4*)&As[kk][ty * 4];
            float4 b4 = *(const float4*)&Bs[kk][tx * 4];
            float av[4] = {a4.x, a4.y, a4.z, a4.w};
            float bv[4] = {b4.x, b4.y, b4.z, b4.w};
#pragma unroll
            for (int i = 0; i < 4; ++i)
#pragma unroll
                for (int j = 0; j < 4; ++j)
                    acc[i][j] = fmaf(av[i], bv[j], acc[i][j]);
        }
        __syncthreads();
    }

    // ---- epilogue: +bias, relu, +addsrc, float4 store ----
#pragma unroll
    for (int i = 0; i < 4; ++i) {
        int m = m0 + ty * 4 + i;
        if (m >= M) continue;
        float bsv = bias[m];
        float vals[4];
#pragma unroll
        for (int j = 0; j < 4; ++j) {
            float v = acc[i][j] + bsv;
            if (relu) v = fmaxf(v, 0.f);
            vals[j] = v;
        }
        if (addsrc) {
            const float4 ad = *(const float4*)(addsrc + (size_t)m * NPIX + n0 + tx * 4);
            vals[0] += ad.x; vals[1] += ad.y; vals[2] += ad.z; vals[3] += ad.w;
        }
        float4 out; out.x = vals[0]; out.y = vals[1]; out.z = vals[2]; out.w = vals[3];
        *(float4*)(C + (size_t)m * NPIX + n0 + tx * 4) = out;
    }
}

// ---------------------------------------------------------------------------
// im2col: im[k][n], k = ci*9 + (dy+1)*3 + (dx+1), matching W1's [o][ci][ky][kx]
// flattening. Zero padding at image borders (per batch image).
// ---------------------------------------------------------------------------
__global__ __launch_bounds__(256) void im2col_k(
    const float* __restrict__ S, float* __restrict__ im)
{
    int idx = blockIdx.x * 256 + threadIdx.x;
    if (idx >= 720 * NPIX) return;
    int k = idx >> 13;          // / 8192
    int n = idx & (NPIX - 1);
    int ci = k / 9;
    int t  = k - ci * 9;
    int dy = t / 3 - 1, dx = t - (t / 3) * 3 - 1;
    int b = n >> 10, r = n & 1023;
    int y = (r >> 5) + dy, x = (r & 31) + dx;
    float v = 0.f;
    if ((unsigned)y < 32u && (unsigned)x < 32u)
        v = S[(size_t)ci * NPIX + b * 1024 + y * 32 + x];
    im[idx] = v;
}

// ---------------------------------------------------------------------------
// 3x3 SAME maxpool on channel 0 of S at flat pixel n.
// ---------------------------------------------------------------------------
__device__ inline float pool3(const float* __restrict__ a0, int n)
{
    int b = n >> 10, r = n & 1023, y = r >> 5, x = r & 31;
    float mx = -1e30f;
#pragma unroll
    for (int dy = -1; dy <= 1; ++dy) {
        int yy = y + dy;
        if ((unsigned)yy >= 32u) continue;
#pragma unroll
        for (int dx = -1; dx <= 1; ++dx) {
            int xx = x + dx;
            if ((unsigned)xx >= 32u) continue;
            mx = fmaxf(mx, a0[b * 1024 + yy * 32 + xx]);
        }
    }
    return mx;
}

__global__ __launch_bounds__(256) void premask_k(
    const float* __restrict__ S, float* __restrict__ mask)
{
    int n = blockIdx.x * 256 + threadIdx.x;
    mask[n] = (pool3(S, n) > T_ALIVE) ? 1.f : 0.f;
}

// Snew = unmasked updated state (buf1); writes masked state into Sout (buf0).
__global__ __launch_bounds__(256) void maskupd_k(
    const float* __restrict__ Snew, const float* __restrict__ pre,
    float* __restrict__ Sout)
{
    int n = blockIdx.x * 256 + threadIdx.x;
    float live = ((pool3(Snew, n) > T_ALIVE) && (pre[n] > 0.5f)) ? 1.f : 0.f;
    for (int c = 0; c < 80; ++c)
        Sout[(size_t)c * NPIX + n] = Snew[(size_t)c * NPIX + n] * live;
}

// WT[k*M + m] = W[m*K + k]
__global__ __launch_bounds__(256) void transpose_k(
    const float* __restrict__ W, float* __restrict__ WT, int M, int K)
{
    int idx = blockIdx.x * 256 + threadIdx.x;
    if (idx >= M * K) return;
    int m = idx / K, k = idx - m * K;
    WT[(size_t)k * M + m] = W[idx];
}

// Seed: state[b][0][16][16]=1, state[b][1+j][16][16]=z[b][j] for j in 0..78.
__global__ __launch_bounds__(256) void seed_k(
    const float* __restrict__ z, float* __restrict__ S)
{
    int idx = blockIdx.x * 256 + threadIdx.x;
    if (idx >= 640) return;
    int b = idx / 80, c = idx - b * 80;
    int n = b * 1024 + 16 * 32 + 16;
    S[(size_t)c * NPIX + n] = (c == 0) ? 1.f : z[b * 100 + (c - 1)];
}

extern "C" void kernel_launch(void* const* d_in, const int* in_sizes, int n_in,
                              void* d_out, int out_size, void* d_ws, size_t ws_size,
                              hipStream_t stream)
{
    const float* z  = (const float*)d_in[0];  // (8,100,1,1)
    const float* W1 = (const float*)d_in[1];  // (512,80,3,3)
    const float* b1 = (const float*)d_in[2];  // (512,)
    const float* W2 = (const float*)d_in[3];  // (512,512,1,1)
    const float* b2 = (const float*)d_in[4];  // (512,)
    const float* W3 = (const float*)d_in[5];  // (80,512,1,1)
    const float* b3 = (const float*)d_in[6];  // (80,)

    float* ws   = (float*)d_ws;
    float* buf0 = ws;                        //  80*8192 current state
    float* buf1 = buf0 + 80 * NPIX;          //  80*8192 unmasked updated state
    float* P    = buf1 + 80 * NPIX;          // 512*8192 perception
    float* SH   = P + 512 * NPIX;            // 720*8192 shared: im2col & hidden
    float* im   = SH;                        //   (disjoint lifetimes in-stream)
    float* Hb   = SH;
    float* mask = SH + 720 * NPIX;           // 8192 pre-living mask
    float* WT1  = mask + NPIX;               // 720*512
    float* WT2  = WT1 + 720 * 512;           // 512*512
    float* WT3  = WT2 + 512 * 512;           // 512*80
    // total: 12,083,200 floats = 48.3 MB

    // init state: zeros + seed (ws is poisoned 0xAA before every call)
    hipMemsetAsync(buf0, 0, (size_t)80 * NPIX * sizeof(float), stream);
    transpose_k<<<(512 * 720 + 255) / 256, 256, 0, stream>>>(W1, WT1, 512, 720);
    transpose_k<<<(512 * 512 + 255) / 256, 256, 0, stream>>>(W2, WT2, 512, 512);
    transpose_k<<<(80 * 512 + 255) / 256, 256, 0, stream>>>(W3, WT3, 80, 512);
    seed_k<<<3, 256, 0, stream>>>(z, buf0);

    dim3 blk(256);
    dim3 g12(NPIX / 64, 512 / 64);   // 128 x 8 blocks
    dim3 g3(NPIX / 64, 2);           // M=80 -> 2 row-blocks (edge guarded)

    for (int s = 0; s < 64; ++s) {
        premask_k<<<NPIX / 256, blk, 0, stream>>>(buf0, mask);
        im2col_k<<<(720 * NPIX) / 256, blk, 0, stream>>>(buf0, im);
        // perception = conv3x3(state) + b1
        gemm64<<<g12, blk, 0, stream>>>(WT1, im, b1, nullptr, P, 512, 720, 0);
        // h = relu(W2 @ perception + b2)
        gemm64<<<g12, blk, 0, stream>>>(WT2, P, b2, nullptr, Hb, 512, 512, 1);
        // buf1 = state + (W3 @ h + b3)
        gemm64<<<g3, blk, 0, stream>>>(WT3, Hb, b3, buf0, buf1, 80, 512, 0);
        // buf0 = buf1 * living
        maskupd_k<<<NPIX / 256, blk, 0, stream>>>(buf1, mask, buf0);
    }

    // output = state[:, 0] = first 8192 floats of buf0 (b,y,x order)
    hipMemcpyAsync(d_out, buf0, NPIX * sizeof(float),
                   hipMemcpyDeviceToDevice, stream);
}

// Round 2
// 4918.364 us; speedup vs baseline: 2.5454x; 2.5454x over previous
//
#include <hip/hip_runtime.h>

// CAGenerator: 64-step neural CA, fp16-MFMA rewrite.
// All GEMMs: D = W(MxK) * Act(KxN), N=8192 pixels, via v_mfma_f32_16x16x32_f16.
// Fragment-order ("swizzled") layouts so that global_load_lds(16B) stages tiles
// with zero address math and ds_read_b128 fragment reads are conflict-free:
//   SW[((kc*T + t)*64 + lane)*8 + j] = Mat[t*16 + (lane&15)][kc*32 + (lane>>4)*8 + j]
// Weights swizzled once per launch; activations (im2col/P/H) written in
// B-fragment order directly by producer kernels' epilogues.
// mask = uniform()<1.0 is always true in the reference -> no RNG.

#define NPIX 8192
#define T_ALIVE 0.01f

typedef _Float16 f16;
typedef __attribute__((ext_vector_type(8))) _Float16 h8_t;
typedef __attribute__((ext_vector_type(4))) _Float16 h4_t;
typedef __attribute__((ext_vector_type(4))) float f4_t;

#define GLDS16(g, l) __builtin_amdgcn_global_load_lds( \
    (const __attribute__((address_space(1))) void*)(g), \
    (__attribute__((address_space(3))) void*)(l), 16, 0, 0)

// ---------------------------------------------------------------------------
// GEMM: 128x128 block tile, 4 waves (64x64 each), BK=32, double-buffered LDS.
// mode 0: out = fp16 B-sw (bias);  mode 1: same + relu;
// mode 2: out = fp32 buf1[c][n] = acc + bias + addsrc, only c<80.
// ---------------------------------------------------------------------------
__global__ __launch_bounds__(256) void gemm_f16(
    const f16* __restrict__ Asw, const f16* __restrict__ Bsw,
    const float* __restrict__ bias, const float* __restrict__ addsrc,
    void* __restrict__ outp, int Kc, int Mt_tot, int mode)
{
    __shared__ f16 A_lds[2][4096];   // 8 mt x 64 lanes x 8 halfs
    __shared__ f16 B_lds[2][4096];   // 8 nt x 64 lanes x 8 halfs

    const int tid  = threadIdx.x;
    const int lane = tid & 63;
    const int w    = tid >> 6;
    const int wm   = w & 1, wn = w >> 1;
    const int nb   = blockIdx.x, mb = blockIdx.y;

    f4_t acc[4][4];
#pragma unroll
    for (int i = 0; i < 4; ++i)
#pragma unroll
        for (int j = 0; j < 4; ++j) acc[i][j] = f4_t{0.f, 0.f, 0.f, 0.f};

    // Each wave stages 4 x 1KB segments: A mtiles {w, w+4}, B ntiles {w, w+4}.
    auto stage = [&](int kc, int d) {
        GLDS16(Asw + (((size_t)kc * Mt_tot + mb * 8 + w    ) * 64 + lane) * 8,
               &A_lds[d][(w    ) * 512]);
        GLDS16(Asw + (((size_t)kc * Mt_tot + mb * 8 + w + 4) * 64 + lane) * 8,
               &A_lds[d][(w + 4) * 512]);
        GLDS16(Bsw + (((size_t)kc * 512    + nb * 8 + w    ) * 64 + lane) * 8,
               &B_lds[d][(w    ) * 512]);
        GLDS16(Bsw + (((size_t)kc * 512    + nb * 8 + w + 4) * 64 + lane) * 8,
               &B_lds[d][(w + 4) * 512]);
    };

    stage(0, 0);
    for (int kc = 0; kc < Kc; ++kc) {
        const int d = kc & 1;
        __syncthreads();                       // drains stage(kc); frees buf d^1
        if (kc + 1 < Kc) stage(kc + 1, d ^ 1); // async prefetch, no wait
        h8_t a[4], b[4];
#pragma unroll
        for (int i = 0; i < 4; ++i)
            a[i] = *(const h8_t*)&A_lds[d][((wm * 4 + i) * 64 + lane) * 8];
#pragma unroll
        for (int j = 0; j < 4; ++j)
            b[j] = *(const h8_t*)&B_lds[d][((wn * 4 + j) * 64 + lane) * 8];
#pragma unroll
        for (int i = 0; i < 4; ++i)
#pragma unroll
            for (int j = 0; j < 4; ++j)
                acc[i][j] = __builtin_amdgcn_mfma_f32_16x16x32_f16(
                    a[i], b[j], acc[i][j], 0, 0, 0);
    }

    // Epilogue. C/D layout: n = lane&15, m = m0 + r with m0 = tile + (lane>>4)*4.
    const int q = lane >> 4, nn = lane & 15;
    if (mode <= 1) {
        f16* out_sw = (f16*)outp;
#pragma unroll
        for (int i = 0; i < 4; ++i) {
            const int m0 = mb * 128 + (wm * 4 + i) * 16 + q * 4;
#pragma unroll
            for (int j = 0; j < 4; ++j) {
                const int nt_g = nb * 8 + wn * 4 + j;
                h4_t v4;
#pragma unroll
                for (int r = 0; r < 4; ++r) {
                    float v = acc[i][j][r] + bias[m0 + r];
                    if (mode == 1) v = fmaxf(v, 0.f);
                    v4[r] = (f16)v;
                }
                // B-sw address for k=m0..m0+3 at pixel-tile nt_g
                f16* dst = out_sw +
                    ((((size_t)(m0 >> 5)) * 512 + nt_g) * 64 +
                     ((m0 >> 3) & 3) * 16 + nn) * 8 + (m0 & 7);
                *(h4_t*)dst = v4;
            }
        }
    } else {
        float* buf1 = (float*)outp;
#pragma unroll
        for (int i = 0; i < 4; ++i) {
            const int m0 = (wm * 4 + i) * 16 + q * 4;
#pragma unroll
            for (int j = 0; j < 4; ++j) {
                const int n = (nb * 8 + wn * 4 + j) * 16 + nn;
#pragma unroll
                for (int r = 0; r < 4; ++r) {
                    const int m = m0 + r;
                    if (m < 80) {
                        const size_t idx = (size_t)m * NPIX + n;
                        buf1[idx] = acc[i][j][r] + bias[m] + addsrc[idx];
                    }
                }
            }
        }
    }
}

// ---------------------------------------------------------------------------
// im2col into B-fragment order fp16. k = ci*9 + (dy+1)*3 + (dx+1), Kpad=736.
// ---------------------------------------------------------------------------
__global__ __launch_bounds__(256) void im2col_sw(
    const float* __restrict__ S, f16* __restrict__ im)
{
    const int idx = blockIdx.x * 256 + threadIdx.x;   // < 23*512*64
    const int kc = idx >> 15;
    const int rem = idx & 32767;
    const int nt = rem >> 6, lane = rem & 63;
    const int n = nt * 16 + (lane & 15);
    const int b = n >> 10, y0 = (n & 1023) >> 5, x0 = n & 31;
    const int k0 = kc * 32 + (lane >> 4) * 8;
    h8_t v;
#pragma unroll
    for (int j = 0; j < 8; ++j) {
        const int k = k0 + j;
        float val = 0.f;
        if (k < 720) {
            const int ci = k / 9, t9 = k - ci * 9;
            const int y = y0 + t9 / 3 - 1, x = x0 + (t9 % 3) - 1;
            if ((unsigned)y < 32u && (unsigned)x < 32u)
                val = S[(size_t)ci * NPIX + b * 1024 + y * 32 + x];
        }
        v[j] = (f16)val;
    }
    *(h8_t*)(im + (size_t)idx * 8) = v;
}

// ---------------------------------------------------------------------------
__device__ inline float pool3a(const float* __restrict__ a, int n)
{
    const int b = n >> 10, r = n & 1023, y = r >> 5, x = r & 31;
    float mx = -1e30f;
#pragma unroll
    for (int dy = -1; dy <= 1; ++dy) {
        const int yy = y + dy;
        if ((unsigned)yy >= 32u) continue;
#pragma unroll
        for (int dx = -1; dx <= 1; ++dx) {
            const int xx = x + dx;
            if ((unsigned)xx >= 32u) continue;
            mx = fmaxf(mx, a[b * 1024 + yy * 32 + xx]);
        }
    }
    return mx;
}

__device__ inline bool live_at(const float* __restrict__ buf1,
                               const float* __restrict__ pre, int n)
{
    return (pool3a(buf1, n) > T_ALIVE) && (pre[n] > 0.5f);
}

// Fused: buf0 = buf1 * live; pre_next = (maxpool3(masked alpha) > T).
__global__ __launch_bounds__(256) void maskfuse_k(
    const float* __restrict__ buf1, const float* __restrict__ pre,
    float* __restrict__ buf0, float* __restrict__ pre_next)
{
    const int n = blockIdx.x * 256 + threadIdx.x;
    const float lv = live_at(buf1, pre, n) ? 1.f : 0.f;
    for (int c = 0; c < 80; ++c)
        buf0[(size_t)c * NPIX + n] = buf1[(size_t)c * NPIX + n] * lv;
    const int b = n >> 10, r = n & 1023, y = r >> 5, x = r & 31;
    float mx = -1e30f;
#pragma unroll
    for (int dy = -1; dy <= 1; ++dy) {
        const int yy = y + dy;
        if ((unsigned)yy >= 32u) continue;
#pragma unroll
        for (int dx = -1; dx <= 1; ++dx) {
            const int xx = x + dx;
            if ((unsigned)xx >= 32u) continue;
            const int n2 = b * 1024 + yy * 32 + xx;
            const float ma = live_at(buf1, pre, n2) ? buf1[n2] : 0.f;
            mx = fmaxf(mx, ma);
        }
    }
    pre_next[n] = (mx > T_ALIVE) ? 1.f : 0.f;
}

__global__ __launch_bounds__(256) void premask_init_k(
    const float* __restrict__ S, float* __restrict__ pre)
{
    const int n = blockIdx.x * 256 + threadIdx.x;
    pre[n] = (pool3a(S, n) > T_ALIVE) ? 1.f : 0.f;
}

// Weight swizzle: W (Mreal x Kreal row-major fp32) -> A-fragment-order fp16,
// zero-padded to Mt_tot*16 x Kc*32.
__global__ __launch_bounds__(256) void swz_w(
    const float* __restrict__ W, f16* __restrict__ Asw,
    int Mreal, int Kreal, int Mt_tot, int Kc)
{
    const int idx = blockIdx.x * 256 + threadIdx.x;
    if (idx >= Kc * Mt_tot * 64) return;
    const int lane = idx & 63;
    const int t = idx >> 6;
    const int mt = t % Mt_tot, kc = t / Mt_tot;
    const int m = mt * 16 + (lane & 15);
    const int k0 = kc * 32 + (lane >> 4) * 8;
    h8_t v;
#pragma unroll
    for (int j = 0; j < 8; ++j) {
        const int k = k0 + j;
        const float val = (m < Mreal && k < Kreal) ? W[(size_t)m * Kreal + k] : 0.f;
        v[j] = (f16)val;
    }
    *(h8_t*)(Asw + (size_t)idx * 8) = v;
}

__global__ __launch_bounds__(256) void seed_k(
    const float* __restrict__ z, float* __restrict__ S)
{
    const int idx = blockIdx.x * 256 + threadIdx.x;
    if (idx >= 640) return;
    const int b = idx / 80, c = idx - b * 80;
    const int n = b * 1024 + 16 * 32 + 16;
    S[(size_t)c * NPIX + n] = (c == 0) ? 1.f : z[b * 100 + (c - 1)];
}

extern "C" void kernel_launch(void* const* d_in, const int* in_sizes, int n_in,
                              void* d_out, int out_size, void* d_ws, size_t ws_size,
                              hipStream_t stream)
{
    const float* z  = (const float*)d_in[0];
    const float* W1 = (const float*)d_in[1];   // (512,80,3,3) = 512 x 720
    const float* b1 = (const float*)d_in[2];
    const float* W2 = (const float*)d_in[3];   // 512 x 512
    const float* b2 = (const float*)d_in[4];
    const float* W3 = (const float*)d_in[5];   // 80 x 512
    const float* b3 = (const float*)d_in[6];

    char* ws = (char*)d_ws;
    float* buf0 = (float*)ws;                          ws += (size_t)80 * NPIX * 4;
    float* buf1 = (float*)ws;                          ws += (size_t)80 * NPIX * 4;
    float* preA = (float*)ws;                          ws += NPIX * 4;
    float* preB = (float*)ws;                          ws += NPIX * 4;
    f16* A1sw = (f16*)ws;                              ws += (size_t)23 * 32 * 512 * 2;
    f16* A2sw = (f16*)ws;                              ws += (size_t)16 * 32 * 512 * 2;
    f16* A3sw = (f16*)ws;                              ws += (size_t)16 * 8 * 512 * 2;
    f16* im   = (f16*)ws;                              ws += (size_t)23 * 512 * 512 * 2;
    f16* P    = (f16*)ws;                              ws += (size_t)16 * 512 * 512 * 2;
    f16* Hb   = (f16*)ws;                              ws += (size_t)16 * 512 * 512 * 2;
    // total ~35.5 MB

    hipMemsetAsync(buf0, 0, (size_t)80 * NPIX * 4, stream);
    seed_k<<<3, 256, 0, stream>>>(z, buf0);
    swz_w<<<184, 256, 0, stream>>>(W1, A1sw, 512, 720, 32, 23);
    swz_w<<<128, 256, 0, stream>>>(W2, A2sw, 512, 512, 32, 16);
    swz_w<<<32, 256, 0, stream>>>(W3, A3sw, 80, 512, 8, 16);
    premask_init_k<<<NPIX / 256, 256, 0, stream>>>(buf0, preA);
    im2col_sw<<<2944, 256, 0, stream>>>(buf0, im);

    float* pre_cur = preA;
    float* pre_nxt = preB;
    for (int s = 0; s < 64; ++s) {
        gemm_f16<<<dim3(64, 4), 256, 0, stream>>>(A1sw, im, b1, nullptr, P, 23, 32, 0);
        gemm_f16<<<dim3(64, 4), 256, 0, stream>>>(A2sw, P, b2, nullptr, Hb, 16, 32, 1);
        gemm_f16<<<dim3(64, 1), 256, 0, stream>>>(A3sw, Hb, b3, buf0, buf1, 16, 8, 2);
        maskfuse_k<<<NPIX / 256, 256, 0, stream>>>(buf1, pre_cur, buf0, pre_nxt);
        float* t = pre_cur; pre_cur = pre_nxt; pre_nxt = t;
        im2col_sw<<<2944, 256, 0, stream>>>(buf0, im);
    }

    hipMemcpyAsync(d_out, buf0, NPIX * sizeof(float),
                   hipMemcpyDeviceToDevice, stream);
}